// Round 2
// baseline (17027.054 us; speedup 1.0000x reference)
//
#include <hip/hip_runtime.h>
#include <hip/hip_bf16.h>

// BDLOTreeLSTM on MI355X — round 2: fix GPU fault (workspace overflow).
// All big activations stored as bf16 -> ws = 3 * NROWS * Hd * 2 B ~ 151 MB.

constexpr int Hd    = 256;
constexpr int NBv   = 3;
constexpr int NVv   = 64;
constexpr int BATCH = 512;
constexpr long long NROWS = (long long)BATCH * NBv * NVv;   // 98304
constexpr int BPB = 4;          // batch elements per block in seq kernel
constexpr int CLEN = 40;        // chain length (CS = (40,40))
constexpr int CI0 = 16, CI1 = 48; // COUP

typedef __hip_bfloat16 bf16;

__device__ __forceinline__ float sigf(float x)   { return 1.f / (1.f + __expf(-x)); }
__device__ __forceinline__ float tanh_f(float x) { return 1.f - 2.f / (__expf(2.f * x) + 1.f); }

// ---------------- fused encoder: enc = relu(feats@w1+b1)@w2 + b2, feats on the fly
__global__ __launch_bounds__(256) void enc_kernel(
    const float* __restrict__ cv, const float* __restrict__ pv,
    const float* __restrict__ hints,
    const float* __restrict__ w1, const float* __restrict__ b1,
    const float* __restrict__ w2, const float* __restrict__ b2,
    bf16* __restrict__ enc)
{
  __shared__ float fs[8][9];
  __shared__ float h1s[8][Hd];
  long long row0 = (long long)blockIdx.x * 8;
  int tid = threadIdx.x;
  if (tid < 72) {
    int r = tid / 9, i = tid % 9;
    long long row = row0 + r;
    float v;
    if (i < 3)      v = cv[row * 3 + i];
    else if (i < 6) v = cv[row * 3 + (i - 3)] - pv[row * 3 + (i - 3)];
    else            v = hints[row * 3 + (i - 6)];
    fs[r][i] = v;
  }
  __syncthreads();
  int j = tid;
  {
    float w[9];
#pragma unroll
    for (int i = 0; i < 9; i++) w[i] = w1[i * Hd + j];
    float bb = b1[j];
#pragma unroll
    for (int r = 0; r < 8; r++) {
      float a = bb;
#pragma unroll
      for (int i = 0; i < 9; i++) a += fs[r][i] * w[i];
      h1s[r][j] = fmaxf(a, 0.f);
    }
  }
  __syncthreads();
  float acc[8];
  float bb2 = b2[j];
#pragma unroll
  for (int r = 0; r < 8; r++) acc[r] = bb2;
  for (int t = 0; t < Hd; t++) {
    float w = w2[t * Hd + j];
#pragma unroll
    for (int r = 0; r < 8; r++) acc[r] += h1s[r][t] * w;
  }
#pragma unroll
  for (int r = 0; r < 8; r++) enc[(row0 + r) * Hd + j] = __float2bfloat16(acc[r]);
}

// ---------------- the whole recurrent program, batch-parallel
__global__ __launch_bounds__(256) void seq_kernel(
    const bf16* __restrict__ enc,
    const float* __restrict__ W_iou, const float* __restrict__ b_iou,
    const float* __restrict__ U_iou,
    const float* __restrict__ W_f,  const float* __restrict__ b_f,
    const float* __restrict__ U_f,
    const float* __restrict__ W_ih, const float* __restrict__ b_ih,
    const float* __restrict__ W_hh, const float* __restrict__ b_hh,
    bf16* __restrict__ bu_h, bf16* __restrict__ td_h)
{
  __shared__ float x_s[BPB][Hd];
  __shared__ float h_s[BPB][Hd];
  __shared__ float hs_s[BPB][Hd];          // h_sum for parent chain
  __shared__ float rh_s[2][BPB][Hd];       // chain roots' h (needed across t)

  int j  = threadIdx.x;
  int b0 = blockIdx.x * BPB;

  float bi0 = b_iou[j], bi1 = b_iou[Hd + j], bi2 = b_iou[2 * Hd + j], bf0 = b_f[j];

  float c_reg[BPB];
  float rc_reg[2][BPB];                    // chain roots' c (elementwise only)
  float sh_reg[2][BPB], sc_reg[2][BPB];    // td seeds at COUP vertices

  // ===== bottom-up chains (k = 0,1; branch k+1; vertices 39..0) =====
  for (int k = 0; k < 2; k++) {
#pragma unroll
    for (int r = 0; r < BPB; r++) { h_s[r][j] = 0.f; c_reg[r] = 0.f; }
    __syncthreads();
    for (int v = CLEN - 1; v >= 0; --v) {
#pragma unroll
      for (int r = 0; r < BPB; r++)
        x_s[r][j] = __bfloat162float(enc[(((long long)(b0 + r) * NBv + (k + 1)) * NVv + v) * Hd + j]);
      __syncthreads();
      float ai[BPB], ao[BPB], au[BPB], af[BPB];
#pragma unroll
      for (int r = 0; r < BPB; r++) { ai[r] = bi0; ao[r] = bi1; au[r] = bi2; af[r] = bf0; }
      for (int t = 0; t < Hd; t++) {
        float w0 = W_iou[t * 768 + j], w1v = W_iou[t * 768 + Hd + j], w2v = W_iou[t * 768 + 2 * Hd + j];
        float u0 = U_iou[t * 768 + j], u1v = U_iou[t * 768 + Hd + j], u2v = U_iou[t * 768 + 2 * Hd + j];
        float wf = W_f[t * Hd + j],    uf  = U_f[t * Hd + j];
#pragma unroll
        for (int r = 0; r < BPB; r++) {
          float xt = x_s[r][t], ht = h_s[r][t];
          ai[r] += xt * w0  + ht * u0;
          ao[r] += xt * w1v + ht * u1v;
          au[r] += xt * w2v + ht * u2v;
          af[r] += xt * wf  + ht * uf;
        }
      }
      __syncthreads();
#pragma unroll
      for (int r = 0; r < BPB; r++) {
        float cn = sigf(ai[r]) * tanh_f(au[r]) + sigf(af[r]) * c_reg[r];
        float hn = sigf(ao[r]) * tanh_f(cn);
        c_reg[r] = cn;
        h_s[r][j] = hn;
        bu_h[(((long long)(b0 + r) * NBv + (k + 1)) * NVv + v) * Hd + j] = __float2bfloat16(hn);
        if (v == 0) { rh_s[k][r][j] = hn; rc_reg[k][r] = cn; }
      }
      __syncthreads();
    }
  }

  // ===== bottom-up parent chain (branch 0; vertices 63..0) =====
#pragma unroll
  for (int r = 0; r < BPB; r++) { h_s[r][j] = 0.f; c_reg[r] = 0.f; }
  __syncthreads();
  for (int v = NVv - 1; v >= 0; --v) {
    int ck = (v == CI0) ? 0 : ((v == CI1) ? 1 : -1);
#pragma unroll
    for (int r = 0; r < BPB; r++) {
      x_s[r][j] = __bfloat162float(enc[(((long long)(b0 + r) * NBv) * NVv + v) * Hd + j]);
      float hsum = h_s[r][j];
      if (ck >= 0) hsum += rh_s[ck][r][j];
      hs_s[r][j] = hsum;
    }
    __syncthreads();
    float ai[BPB], ao[BPB], au[BPB], awf[BPB], ahf[BPB], acf[BPB];
#pragma unroll
    for (int r = 0; r < BPB; r++) {
      ai[r] = bi0; ao[r] = bi1; au[r] = bi2; awf[r] = bf0; ahf[r] = 0.f; acf[r] = 0.f;
    }
    for (int t = 0; t < Hd; t++) {
      float w0 = W_iou[t * 768 + j], w1v = W_iou[t * 768 + Hd + j], w2v = W_iou[t * 768 + 2 * Hd + j];
      float u0 = U_iou[t * 768 + j], u1v = U_iou[t * 768 + Hd + j], u2v = U_iou[t * 768 + 2 * Hd + j];
      float wf = W_f[t * Hd + j],    uf  = U_f[t * Hd + j];
#pragma unroll
      for (int r = 0; r < BPB; r++) {
        float xt = x_s[r][t], hst = hs_s[r][t], ht = h_s[r][t];
        ai[r] += xt * w0  + hst * u0;
        ao[r] += xt * w1v + hst * u1v;
        au[r] += xt * w2v + hst * u2v;
        awf[r] += xt * wf;
        ahf[r] += ht * uf;
        if (ck >= 0) acf[r] += rh_s[ck][r][t] * uf;
      }
    }
    __syncthreads();
#pragma unroll
    for (int r = 0; r < BPB; r++) {
      float fc = sigf(awf[r] + ahf[r]) * c_reg[r];
      if (ck >= 0) fc += sigf(awf[r] + acf[r]) * rc_reg[ck][r];
      float cn = sigf(ai[r]) * tanh_f(au[r]) + fc;
      float hn = sigf(ao[r]) * tanh_f(cn);
      c_reg[r] = cn;
      h_s[r][j] = hn;
      bu_h[(((long long)(b0 + r) * NBv) * NVv + v) * Hd + j] = __float2bfloat16(hn);
    }
    __syncthreads();
  }

  // h_s / c_reg now hold parent vertex-0 state == top-down seed
  float bih0 = b_ih[j]          + b_hh[j];
  float bih1 = b_ih[Hd + j]     + b_hh[Hd + j];
  float bih2 = b_ih[2 * Hd + j] + b_hh[2 * Hd + j];
  float bih3 = b_ih[3 * Hd + j] + b_hh[3 * Hd + j];

#pragma unroll
  for (int r = 0; r < BPB; r++)
    td_h[(((long long)(b0 + r) * NBv) * NVv + 0) * Hd + j] = __float2bfloat16(h_s[r][j]);

  // ===== top-down parent chain (vertices 1..63) =====
  for (int v = 1; v < NVv; ++v) {
#pragma unroll
    for (int r = 0; r < BPB; r++)
      x_s[r][j] = __bfloat162float(enc[(((long long)(b0 + r) * NBv) * NVv + v) * Hd + j]);
    __syncthreads();
    float gi[BPB], gf[BPB], gg[BPB], go[BPB];
#pragma unroll
    for (int r = 0; r < BPB; r++) { gi[r] = bih0; gf[r] = bih1; gg[r] = bih2; go[r] = bih3; }
    for (int t = 0; t < Hd; t++) {
      float wi0 = W_ih[t * 1024 + j], wi1 = W_ih[t * 1024 + Hd + j];
      float wi2 = W_ih[t * 1024 + 2 * Hd + j], wi3 = W_ih[t * 1024 + 3 * Hd + j];
      float wh0 = W_hh[t * 1024 + j], wh1 = W_hh[t * 1024 + Hd + j];
      float wh2 = W_hh[t * 1024 + 2 * Hd + j], wh3 = W_hh[t * 1024 + 3 * Hd + j];
#pragma unroll
      for (int r = 0; r < BPB; r++) {
        float xt = x_s[r][t], ht = h_s[r][t];
        gi[r] += xt * wi0 + ht * wh0;
        gf[r] += xt * wi1 + ht * wh1;
        gg[r] += xt * wi2 + ht * wh2;
        go[r] += xt * wi3 + ht * wh3;
      }
    }
    __syncthreads();
#pragma unroll
    for (int r = 0; r < BPB; r++) {
      float cn = sigf(gf[r]) * c_reg[r] + sigf(gi[r]) * tanh_f(gg[r]);
      float hn = sigf(go[r]) * tanh_f(cn);
      c_reg[r] = cn;
      h_s[r][j] = hn;
      td_h[(((long long)(b0 + r) * NBv) * NVv + v) * Hd + j] = __float2bfloat16(hn);
      if (v == CI0) { sh_reg[0][r] = hn; sc_reg[0][r] = cn; }
      if (v == CI1) { sh_reg[1][r] = hn; sc_reg[1][r] = cn; }
    }
    __syncthreads();
  }

  // ===== top-down chains (k = 0,1; branch k+1; vertices 0..39) =====
  for (int k = 0; k < 2; k++) {
#pragma unroll
    for (int r = 0; r < BPB; r++) { h_s[r][j] = sh_reg[k][r]; c_reg[r] = sc_reg[k][r]; }
    __syncthreads();
    for (int v = 0; v < CLEN; ++v) {
#pragma unroll
      for (int r = 0; r < BPB; r++)
        x_s[r][j] = __bfloat162float(enc[(((long long)(b0 + r) * NBv + (k + 1)) * NVv + v) * Hd + j]);
      __syncthreads();
      float gi[BPB], gf[BPB], gg[BPB], go[BPB];
#pragma unroll
      for (int r = 0; r < BPB; r++) { gi[r] = bih0; gf[r] = bih1; gg[r] = bih2; go[r] = bih3; }
      for (int t = 0; t < Hd; t++) {
        float wi0 = W_ih[t * 1024 + j], wi1 = W_ih[t * 1024 + Hd + j];
        float wi2 = W_ih[t * 1024 + 2 * Hd + j], wi3 = W_ih[t * 1024 + 3 * Hd + j];
        float wh0 = W_hh[t * 1024 + j], wh1 = W_hh[t * 1024 + Hd + j];
        float wh2 = W_hh[t * 1024 + 2 * Hd + j], wh3 = W_hh[t * 1024 + 3 * Hd + j];
#pragma unroll
        for (int r = 0; r < BPB; r++) {
          float xt = x_s[r][t], ht = h_s[r][t];
          gi[r] += xt * wi0 + ht * wh0;
          gf[r] += xt * wi1 + ht * wh1;
          gg[r] += xt * wi2 + ht * wh2;
          go[r] += xt * wi3 + ht * wh3;
        }
      }
      __syncthreads();
#pragma unroll
      for (int r = 0; r < BPB; r++) {
        float cn = sigf(gf[r]) * c_reg[r] + sigf(gi[r]) * tanh_f(gg[r]);
        float hn = sigf(go[r]) * tanh_f(cn);
        c_reg[r] = cn;
        h_s[r][j] = hn;
        td_h[(((long long)(b0 + r) * NBv + (k + 1)) * NVv + v) * Hd + j] = __float2bfloat16(hn);
      }
      __syncthreads();
    }
  }
}

// ---------------- decoder: out = (cv + relu([bu_h,td_h]@w1+b1)@w2 + b2) * mask
__global__ __launch_bounds__(256) void dec_kernel(
    const bf16* __restrict__ bu_h, const bf16* __restrict__ td_h,
    const float* __restrict__ cv,
    const float* __restrict__ w1, const float* __restrict__ b1,
    const float* __restrict__ w2, const float* __restrict__ b2,
    float* __restrict__ out)
{
  __shared__ float comb[8][2 * Hd];
  __shared__ float hid[8][Hd];
  __shared__ float red[4][3];
  long long row0 = (long long)blockIdx.x * 8;
  int j = threadIdx.x;
#pragma unroll
  for (int r = 0; r < 8; r++) {
    comb[r][j]      = __bfloat162float(bu_h[(row0 + r) * Hd + j]);
    comb[r][Hd + j] = __bfloat162float(td_h[(row0 + r) * Hd + j]);
  }
  __syncthreads();
  float acc[8];
  float bb = b1[j];
#pragma unroll
  for (int r = 0; r < 8; r++) acc[r] = bb;
  for (int t = 0; t < 2 * Hd; t++) {
    float w = w1[t * Hd + j];
#pragma unroll
    for (int r = 0; r < 8; r++) acc[r] += comb[r][t] * w;
  }
#pragma unroll
  for (int r = 0; r < 8; r++) hid[r][j] = fmaxf(acc[r], 0.f);
  __syncthreads();

  float w20 = w2[j * 3 + 0], w21 = w2[j * 3 + 1], w22 = w2[j * 3 + 2];
  int wid = j >> 6, lane = j & 63;
  for (int r = 0; r < 8; r++) {
    float h = hid[r][j];
    float p0 = h * w20, p1 = h * w21, p2 = h * w22;
#pragma unroll
    for (int off = 32; off > 0; off >>= 1) {
      p0 += __shfl_down(p0, off);
      p1 += __shfl_down(p1, off);
      p2 += __shfl_down(p2, off);
    }
    if (lane == 0) { red[wid][0] = p0; red[wid][1] = p1; red[wid][2] = p2; }
    __syncthreads();
    if (j < 3) {
      long long row = row0 + r;
      int v  = (int)(row % NVv);
      int br = (int)((row / NVv) % NBv);
      float res = 0.f;
      if (br == 0 || v < CLEN) {
        float s = red[0][j] + red[1][j] + red[2][j] + red[3][j];
        res = cv[row * 3 + j] + s + b2[j];
      }
      out[row * 3 + j] = res;
    }
    __syncthreads();
  }
}

extern "C" void kernel_launch(void* const* d_in, const int* in_sizes, int n_in,
                              void* d_out, int out_size, void* d_ws, size_t ws_size,
                              hipStream_t stream) {
  const float* cv     = (const float*)d_in[0];
  const float* pv     = (const float*)d_in[1];
  const float* hints  = (const float*)d_in[2];
  const float* enc_w1 = (const float*)d_in[3];
  const float* enc_b1 = (const float*)d_in[4];
  const float* enc_w2 = (const float*)d_in[5];
  const float* enc_b2 = (const float*)d_in[6];
  const float* W_iou  = (const float*)d_in[7];
  const float* b_iou  = (const float*)d_in[8];
  const float* U_iou  = (const float*)d_in[9];
  const float* W_f    = (const float*)d_in[10];
  const float* b_f    = (const float*)d_in[11];
  const float* U_f    = (const float*)d_in[12];
  const float* W_ih   = (const float*)d_in[13];
  const float* b_ih   = (const float*)d_in[14];
  const float* W_hh   = (const float*)d_in[15];
  const float* b_hh   = (const float*)d_in[16];
  const float* dec_w1 = (const float*)d_in[17];
  const float* dec_b1 = (const float*)d_in[18];
  const float* dec_w2 = (const float*)d_in[19];
  const float* dec_b2 = (const float*)d_in[20];

  // ws layout: [enc | td_h | bu_h], each NROWS*Hd bf16 (~50.3 MB each, 151 MB total)
  size_t buf_elems = (size_t)NROWS * Hd;
  if (ws_size < 3 * buf_elems * sizeof(bf16)) return;  // diagnosable: out stays 0
  bf16* enc = (bf16*)d_ws;
  bf16* tdh = enc + buf_elems;
  bf16* buh = tdh + buf_elems;

  enc_kernel<<<(int)(NROWS / 8), 256, 0, stream>>>(cv, pv, hints, enc_w1, enc_b1,
                                                   enc_w2, enc_b2, enc);
  seq_kernel<<<BATCH / BPB, 256, 0, stream>>>(enc, W_iou, b_iou, U_iou, W_f, b_f, U_f,
                                              W_ih, b_ih, W_hh, b_hh, buh, tdh);
  dec_kernel<<<(int)(NROWS / 8), 256, 0, stream>>>(buh, tdh, cv, dec_w1, dec_b1,
                                                   dec_w2, dec_b2, (float*)d_out);
}

// Round 3
// 5250.946 us; speedup vs baseline: 3.2427x; 3.2427x over previous
//
#include <hip/hip_runtime.h>
#include <hip/hip_bf16.h>

// BDLOTreeLSTM on MI355X — round 3: MFMA-based seq kernel.
// seq: 32 blocks x 512 threads (BPB=16 batch/block, 8 waves). Per step one
// GEMM [16 x 512(x|h)] @ [512 x 1024] via mfma_f32_16x16x32_bf16, weights
// pre-packed in B-fragment order (coalesced dwordx4 straight from L2).

constexpr int Hd    = 256;
constexpr int NBv   = 3;
constexpr int NVv   = 64;
constexpr int BATCH = 512;
constexpr long long NROWS = (long long)BATCH * NBv * NVv;   // 98304
constexpr int CLEN = 40;
constexpr int CI0 = 16, CI1 = 48;

typedef __hip_bfloat16 bf16;
typedef unsigned short ushort;
typedef __attribute__((ext_vector_type(8))) short short8;
typedef __attribute__((ext_vector_type(4))) float f32x4;

__device__ __forceinline__ float sigf(float x)   { return 1.f / (1.f + __expf(-x)); }
__device__ __forceinline__ float tanh_f(float x) { return 1.f - 2.f / (__expf(2.f * x) + 1.f); }

__device__ __forceinline__ ushort f2bf(float x) {
  unsigned u = __float_as_uint(x);
  return (ushort)((u + 0x7FFFu + ((u >> 16) & 1u)) >> 16);   // RNE
}

// ================= weight packing: composite matrices in MFMA B-frag order ====
// B-frag for mfma_16x16x32: lane l holds B[k][n], k = ks*32 + (l>>4)*8 + j,
// n = nt*16 + (l&15). Packed: out[((nt*NKS + ks)*64 + l)*8 + j].

__global__ __launch_bounds__(256) void pack_bu_kernel(
    const float* __restrict__ W_iou, const float* __restrict__ W_f,
    const float* __restrict__ U_iou, const float* __restrict__ U_f,
    ushort* __restrict__ out)   // [512 K][1024 N]: [[W_iou|W_f];[U_iou|U_f]]
{
  int idx = blockIdx.x * 256 + threadIdx.x;          // 0 .. 512*1024-1
  int j = idx & 7, l = (idx >> 3) & 63, T = idx >> 9;
  int ks = T & 15, nt = T >> 4;
  int k = ks * 32 + (l >> 4) * 8 + j;
  int n = nt * 16 + (l & 15);
  float v;
  if (k < 256) v = (n < 768) ? W_iou[k * 768 + n] : W_f[k * 256 + (n - 768)];
  else         v = (n < 768) ? U_iou[(k - 256) * 768 + n] : U_f[(k - 256) * 256 + (n - 768)];
  out[idx] = f2bf(v);
}

__global__ __launch_bounds__(256) void pack_td_kernel(
    const float* __restrict__ W_ih, const float* __restrict__ W_hh,
    ushort* __restrict__ out)   // [512][1024]: [[W_ih];[W_hh]]
{
  int idx = blockIdx.x * 256 + threadIdx.x;
  int j = idx & 7, l = (idx >> 3) & 63, T = idx >> 9;
  int ks = T & 15, nt = T >> 4;
  int k = ks * 32 + (l >> 4) * 8 + j;
  int n = nt * 16 + (l & 15);
  float v = (k < 256) ? W_ih[k * 1024 + n] : W_hh[(k - 256) * 1024 + n];
  out[idx] = f2bf(v);
}

__global__ __launch_bounds__(256) void pack_wfx_kernel(
    const float* __restrict__ W_f, ushort* __restrict__ out)   // [256][256]
{
  int idx = blockIdx.x * 256 + threadIdx.x;          // 0 .. 256*256-1
  int j = idx & 7, l = (idx >> 3) & 63, T = idx >> 9;
  int ks = T & 7, nt = T >> 3;
  int k = ks * 32 + (l >> 4) * 8 + j;
  int n = nt * 16 + (l & 15);
  out[idx] = f2bf(W_f[k * 256 + n]);
}

// ================= fused encoder (round-2, known-good) ========================
__global__ __launch_bounds__(256) void enc_kernel(
    const float* __restrict__ cv, const float* __restrict__ pv,
    const float* __restrict__ hints,
    const float* __restrict__ w1, const float* __restrict__ b1,
    const float* __restrict__ w2, const float* __restrict__ b2,
    bf16* __restrict__ enc)
{
  __shared__ float fs[8][9];
  __shared__ float h1s[8][Hd];
  long long row0 = (long long)blockIdx.x * 8;
  int tid = threadIdx.x;
  if (tid < 72) {
    int r = tid / 9, i = tid % 9;
    long long row = row0 + r;
    float v;
    if (i < 3)      v = cv[row * 3 + i];
    else if (i < 6) v = cv[row * 3 + (i - 3)] - pv[row * 3 + (i - 3)];
    else            v = hints[row * 3 + (i - 6)];
    fs[r][i] = v;
  }
  __syncthreads();
  int j = tid;
  {
    float w[9];
#pragma unroll
    for (int i = 0; i < 9; i++) w[i] = w1[i * Hd + j];
    float bb = b1[j];
#pragma unroll
    for (int r = 0; r < 8; r++) {
      float a = bb;
#pragma unroll
      for (int i = 0; i < 9; i++) a += fs[r][i] * w[i];
      h1s[r][j] = fmaxf(a, 0.f);
    }
  }
  __syncthreads();
  float acc[8];
  float bb2 = b2[j];
#pragma unroll
  for (int r = 0; r < 8; r++) acc[r] = bb2;
  for (int t = 0; t < Hd; t++) {
    float w = w2[t * Hd + j];
#pragma unroll
    for (int r = 0; r < 8; r++) acc[r] += h1s[r][t] * w;
  }
#pragma unroll
  for (int r = 0; r < 8; r++) enc[(row0 + r) * Hd + j] = __float2bfloat16(acc[r]);
}

// ================= the recurrent program, MFMA edition ========================
// A-tile LDS layout (Ax: x-part K 0..255, Ah: h-part): [16 rows][256 bf16],
// row stride 512 B, XOR-swizzled: byte ^= (row&7)<<4 (kills 16-way conflicts).

#define LDSA(BUF, KS) \
  (*(const short8*)((const char*)(BUF) + (((col) * 512 + ((KS) * 32 + krow * 8) * 2) ^ ((col & 7) << 4))))

#define LDB(W, TILE) (*(const short8*)((W) + ((long long)((TILE) * 64 + lane)) * 8))

#define ZACC42(A) { \
  _Pragma("unroll") for (int g_ = 0; g_ < 4; ++g_) \
  _Pragma("unroll") for (int p_ = 0; p_ < 2; ++p_) A[g_][p_] = zf4; }

#define GEMM_N1024(W, ACC) \
  _Pragma("unroll 4") \
  for (int ks = 0; ks < 16; ++ks) { \
    short8 a_ = (ks < 8) ? LDSA(Ax, ks) : LDSA(Ah, ks - 8); \
    _Pragma("unroll") for (int g = 0; g < 4; ++g) { \
      _Pragma("unroll") for (int p = 0; p < 2; ++p) { \
        short8 b_ = LDB(W, (g * 16 + 2 * w + p) * 16 + ks); \
        ACC[g][p] = __builtin_amdgcn_mfma_f32_16x16x32_bf16(a_, b_, ACC[g][p], 0, 0, 0); \
      } } }

#define GEMM_SIDE(ACC, RBUF) \
  _Pragma("unroll 4") \
  for (int ks = 0; ks < 8; ++ks) { \
    short8 a_ = LDSA(RBUF, ks); \
    _Pragma("unroll") for (int g = 0; g < 4; ++g) { \
      _Pragma("unroll") for (int p = 0; p < 2; ++p) { \
        short8 b_ = LDB(Wbu, (g * 16 + 2 * w + p) * 16 + 8 + ks); \
        ACC[g][p] = __builtin_amdgcn_mfma_f32_16x16x32_bf16(a_, b_, ACC[g][p], 0, 0, 0); \
      } } }

__global__ __launch_bounds__(512) void seq_kernel(
    const ushort* enc,                      // aliases td_h -> no __restrict__
    const ushort* __restrict__ Wbu, const ushort* __restrict__ Wtd,
    const ushort* __restrict__ Wfx,
    const float* __restrict__ b_iou, const float* __restrict__ b_f,
    const float* __restrict__ b_ih,  const float* __restrict__ b_hh,
    ushort* __restrict__ bu_h, ushort* td_h)
{
  __shared__ ushort Ax[16 * 256];
  __shared__ ushort Ah[16 * 256];
  __shared__ ushort Rh[2][16 * 256];

  const int tid  = threadIdx.x;
  const int lane = tid & 63;
  const int w    = tid >> 6;        // wave 0..7
  const int b0   = blockIdx.x * 16;
  const int col  = lane & 15;       // A/D row is (lane&15) for A, col for D
  const int krow = lane >> 4;
  const f32x4 zf4 = {0.f, 0.f, 0.f, 0.f};

  // epilogue ownership: rows r = krow*4+q (q 0..3), cols jj = (2w+p)*16+col (p 0..1)
  float bi0[2], bi1[2], bi2[2], bfv[2], bt0[2], bt1[2], bt2[2], bt3[2];
#pragma unroll
  for (int p = 0; p < 2; ++p) {
    int jj = (2 * w + p) * 16 + col;
    bi0[p] = b_iou[jj]; bi1[p] = b_iou[256 + jj]; bi2[p] = b_iou[512 + jj];
    bfv[p] = b_f[jj];
    bt0[p] = b_ih[jj]       + b_hh[jj];
    bt1[p] = b_ih[256 + jj] + b_hh[256 + jj];
    bt2[p] = b_ih[512 + jj] + b_hh[512 + jj];
    bt3[p] = b_ih[768 + jj] + b_hh[768 + jj];
  }

  float c_reg[2][4];
  float rc[2][2][4];   // bu-chain root c
  float sc[2][2][4];   // td seeds' c

  // ---- helpers (flat 16B-per-thread patterns; swizzle-consistent) ----
  const int srow  = tid >> 5;        // staging row 0..15
  const int schk  = tid & 31;        // 16B chunk in row
  const int sdst  = (srow * 512 + schk * 16) ^ ((srow & 7) << 4);

#define STAGE_X(BR, V) { \
    long long rowg_ = ((long long)(b0 + srow) * NBv + (BR)) * NVv + (V); \
    short8 xv_ = *(const short8*)(enc + rowg_ * 256 + schk * 8); \
    *(short8*)((char*)Ax + sdst) = xv_; }

#define ZERO_AH() { short8 z_ = {0,0,0,0,0,0,0,0}; *(short8*)((char*)Ah + tid * 16) = z_; }
#define COPY_AH(SRC) { *(short8*)((char*)Ah + tid * 16) = *(const short8*)((const char*)(SRC) + tid * 16); }

#define STA(BUF, R, JJ, BITS) { \
    int off_ = ((R) * 512 + (JJ) * 2) ^ (((R) & 7) << 4); \
    (BUF)[off_ >> 1] = (BITS); }

  // ================= bottom-up chains (branch k+1, v 39..0) =================
  for (int k = 0; k < 2; ++k) {
    __syncthreads();
#pragma unroll
    for (int p = 0; p < 2; ++p)
#pragma unroll
      for (int q = 0; q < 4; ++q) c_reg[p][q] = 0.f;
    ZERO_AH();
    for (int v = CLEN - 1; v >= 0; --v) {
      STAGE_X(k + 1, v);
      __syncthreads();
      f32x4 acc[4][2]; ZACC42(acc);
      GEMM_N1024(Wbu, acc);
      __syncthreads();
#pragma unroll
      for (int p = 0; p < 2; ++p) {
        int jj = (2 * w + p) * 16 + col;
#pragma unroll
        for (int q = 0; q < 4; ++q) {
          int r = krow * 4 + q;
          float I = acc[0][p][q] + bi0[p];
          float O = acc[1][p][q] + bi1[p];
          float U = acc[2][p][q] + bi2[p];
          float F = acc[3][p][q] + bfv[p];
          float cn = sigf(I) * tanh_f(U) + sigf(F) * c_reg[p][q];
          float hn = sigf(O) * tanh_f(cn);
          c_reg[p][q] = cn;
          ushort hb = f2bf(hn);
          STA(Ah, r, jj, hb);
          long long rowg = ((long long)(b0 + r) * NBv + (k + 1)) * NVv + v;
          bu_h[rowg * 256 + jj] = hb;
          if (v == 0) { STA(Rh[k], r, jj, hb); rc[k][p][q] = cn; }
        }
      }
    }
  }

  // ================= bottom-up parent chain (branch 0, v 63..0) =============
  __syncthreads();
#pragma unroll
  for (int p = 0; p < 2; ++p)
#pragma unroll
    for (int q = 0; q < 4; ++q) c_reg[p][q] = 0.f;
  ZERO_AH();
  for (int v = NVv - 1; v >= 0; --v) {
    STAGE_X(0, v);
    __syncthreads();
    f32x4 acc[4][2]; ZACC42(acc);
    GEMM_N1024(Wbu, acc);                       // A=[x|h_prev]: iou_prev + f1
    f32x4 accw[2]; accw[0] = zf4; accw[1] = zf4;
#pragma unroll 4
    for (int ks = 0; ks < 8; ++ks) {            // wf_x = x@W_f
      short8 a_ = LDSA(Ax, ks);
#pragma unroll
      for (int p = 0; p < 2; ++p) {
        short8 b_ = LDB(Wfx, (2 * w + p) * 8 + ks);
        accw[p] = __builtin_amdgcn_mfma_f32_16x16x32_bf16(a_, b_, accw[p], 0, 0, 0);
      }
    }
    int ck = (v == CI0) ? 0 : ((v == CI1) ? 1 : -1);
    f32x4 accs[4][2]; ZACC42(accs);
    if (ck == 0) { GEMM_SIDE(accs, Rh[0]); }    // root @ [U_iou|U_f]
    if (ck == 1) { GEMM_SIDE(accs, Rh[1]); }
    __syncthreads();
#pragma unroll
    for (int p = 0; p < 2; ++p) {
      int jj = (2 * w + p) * 16 + col;
#pragma unroll
      for (int q = 0; q < 4; ++q) {
        int r = krow * 4 + q;
        float I  = acc[0][p][q] + bi0[p];
        float O  = acc[1][p][q] + bi1[p];
        float U  = acc[2][p][q] + bi2[p];
        float F1 = acc[3][p][q] + bfv[p];
        float fc = sigf(F1) * c_reg[p][q];
        if (ck >= 0) {
          I += accs[0][p][q]; O += accs[1][p][q]; U += accs[2][p][q];
          float wfx = accw[p][q] + bfv[p];
          fc += sigf(wfx + accs[3][p][q]) * rc[ck][p][q];
        }
        float cn = sigf(I) * tanh_f(U) + fc;
        float hn = sigf(O) * tanh_f(cn);
        c_reg[p][q] = cn;
        ushort hb = f2bf(hn);
        STA(Ah, r, jj, hb);
        long long rowg = ((long long)(b0 + r) * NBv) * NVv + v;
        bu_h[rowg * 256 + jj] = hb;
        if (v == 0) td_h[rowg * 256 + jj] = hb;   // td_h[:,0,0] = seed
      }
    }
  }

  // ================= top-down parent chain (v 1..63), state flows in =========
  for (int v = 1; v < NVv; ++v) {
    STAGE_X(0, v);
    __syncthreads();
    f32x4 acc[4][2]; ZACC42(acc);
    GEMM_N1024(Wtd, acc);
    __syncthreads();
#pragma unroll
    for (int p = 0; p < 2; ++p) {
      int jj = (2 * w + p) * 16 + col;
#pragma unroll
      for (int q = 0; q < 4; ++q) {
        int r = krow * 4 + q;
        float I = acc[0][p][q] + bt0[p];
        float F = acc[1][p][q] + bt1[p];
        float G = acc[2][p][q] + bt2[p];
        float O = acc[3][p][q] + bt3[p];
        float cn = sigf(F) * c_reg[p][q] + sigf(I) * tanh_f(G);
        float hn = sigf(O) * tanh_f(cn);
        c_reg[p][q] = cn;
        ushort hb = f2bf(hn);
        STA(Ah, r, jj, hb);
        long long rowg = ((long long)(b0 + r) * NBv) * NVv + v;
        td_h[rowg * 256 + jj] = hb;
        if (v == CI0) { STA(Rh[0], r, jj, hb); sc[0][p][q] = cn; }
        if (v == CI1) { STA(Rh[1], r, jj, hb); sc[1][p][q] = cn; }
      }
    }
  }

  // ================= top-down chains (branch k+1, v 0..39) ==================
  for (int k = 0; k < 2; ++k) {
    __syncthreads();
    COPY_AH(Rh[k]);
#pragma unroll
    for (int p = 0; p < 2; ++p)
#pragma unroll
      for (int q = 0; q < 4; ++q) c_reg[p][q] = sc[k][p][q];
    for (int v = 0; v < CLEN; ++v) {
      STAGE_X(k + 1, v);
      __syncthreads();
      f32x4 acc[4][2]; ZACC42(acc);
      GEMM_N1024(Wtd, acc);
      __syncthreads();
#pragma unroll
      for (int p = 0; p < 2; ++p) {
        int jj = (2 * w + p) * 16 + col;
#pragma unroll
        for (int q = 0; q < 4; ++q) {
          int r = krow * 4 + q;
          float I = acc[0][p][q] + bt0[p];
          float F = acc[1][p][q] + bt1[p];
          float G = acc[2][p][q] + bt2[p];
          float O = acc[3][p][q] + bt3[p];
          float cn = sigf(F) * c_reg[p][q] + sigf(I) * tanh_f(G);
          float hn = sigf(O) * tanh_f(cn);
          c_reg[p][q] = cn;
          ushort hb = f2bf(hn);
          STA(Ah, r, jj, hb);
          long long rowg = ((long long)(b0 + r) * NBv + (k + 1)) * NVv + v;
          td_h[rowg * 256 + jj] = hb;
        }
      }
    }
  }
}

// ================= decoder (round-2, known-good) ==============================
__global__ __launch_bounds__(256) void dec_kernel(
    const bf16* __restrict__ bu_h, const bf16* __restrict__ td_h,
    const float* __restrict__ cv,
    const float* __restrict__ w1, const float* __restrict__ b1,
    const float* __restrict__ w2, const float* __restrict__ b2,
    float* __restrict__ out)
{
  __shared__ float comb[8][2 * Hd];
  __shared__ float hid[8][Hd];
  __shared__ float red[4][3];
  long long row0 = (long long)blockIdx.x * 8;
  int j = threadIdx.x;
#pragma unroll
  for (int r = 0; r < 8; r++) {
    comb[r][j]      = __bfloat162float(bu_h[(row0 + r) * Hd + j]);
    comb[r][Hd + j] = __bfloat162float(td_h[(row0 + r) * Hd + j]);
  }
  __syncthreads();
  float acc[8];
  float bb = b1[j];
#pragma unroll
  for (int r = 0; r < 8; r++) acc[r] = bb;
  for (int t = 0; t < 2 * Hd; t++) {
    float w = w1[t * Hd + j];
#pragma unroll
    for (int r = 0; r < 8; r++) acc[r] += comb[r][t] * w;
  }
#pragma unroll
  for (int r = 0; r < 8; r++) hid[r][j] = fmaxf(acc[r], 0.f);
  __syncthreads();

  float w20 = w2[j * 3 + 0], w21 = w2[j * 3 + 1], w22 = w2[j * 3 + 2];
  int wid = j >> 6, lane = j & 63;
  for (int r = 0; r < 8; r++) {
    float h = hid[r][j];
    float p0 = h * w20, p1 = h * w21, p2 = h * w22;
#pragma unroll
    for (int off = 32; off > 0; off >>= 1) {
      p0 += __shfl_down(p0, off);
      p1 += __shfl_down(p1, off);
      p2 += __shfl_down(p2, off);
    }
    if (lane == 0) { red[wid][0] = p0; red[wid][1] = p1; red[wid][2] = p2; }
    __syncthreads();
    if (j < 3) {
      long long row = row0 + r;
      int v  = (int)(row % NVv);
      int br = (int)((row / NVv) % NBv);
      float res = 0.f;
      if (br == 0 || v < CLEN) {
        float s = red[0][j] + red[1][j] + red[2][j] + red[3][j];
        res = cv[row * 3 + j] + s + b2[j];
      }
      out[row * 3 + j] = res;
    }
    __syncthreads();
  }
}

extern "C" void kernel_launch(void* const* d_in, const int* in_sizes, int n_in,
                              void* d_out, int out_size, void* d_ws, size_t ws_size,
                              hipStream_t stream) {
  const float* cv     = (const float*)d_in[0];
  const float* pv     = (const float*)d_in[1];
  const float* hints  = (const float*)d_in[2];
  const float* enc_w1 = (const float*)d_in[3];
  const float* enc_b1 = (const float*)d_in[4];
  const float* enc_w2 = (const float*)d_in[5];
  const float* enc_b2 = (const float*)d_in[6];
  const float* W_iou  = (const float*)d_in[7];
  const float* b_iou  = (const float*)d_in[8];
  const float* U_iou  = (const float*)d_in[9];
  const float* W_f    = (const float*)d_in[10];
  const float* b_f    = (const float*)d_in[11];
  const float* U_f    = (const float*)d_in[12];
  const float* W_ih   = (const float*)d_in[13];
  const float* b_ih   = (const float*)d_in[14];
  const float* W_hh   = (const float*)d_in[15];
  const float* b_hh   = (const float*)d_in[16];
  const float* dec_w1 = (const float*)d_in[17];
  const float* dec_b1 = (const float*)d_in[18];
  const float* dec_w2 = (const float*)d_in[19];
  const float* dec_b2 = (const float*)d_in[20];

  // ws (ushorts): enc/td_h alias (NROWS*256) | bu_h (NROWS*256) | Wbu | Wtd | Wfx
  size_t act = (size_t)NROWS * 256;
  size_t need = (2 * act + 2 * (size_t)(512 * 1024) + 256 * 256) * sizeof(ushort);
  if (ws_size < need) return;   // diagnosable: out stays zero

  ushort* encW = (ushort*)d_ws;         // enc, later overwritten in place as td_h
  ushort* buh  = encW + act;
  ushort* Wbu  = buh + act;
  ushort* Wtd  = Wbu + 512 * 1024;
  ushort* Wfx  = Wtd + 512 * 1024;

  pack_bu_kernel<<<2048, 256, 0, stream>>>(W_iou, W_f, U_iou, U_f, Wbu);
  pack_td_kernel<<<2048, 256, 0, stream>>>(W_ih, W_hh, Wtd);
  pack_wfx_kernel<<<256, 256, 0, stream>>>(W_f, Wfx);

  enc_kernel<<<(int)(NROWS / 8), 256, 0, stream>>>(cv, pv, hints, enc_w1, enc_b1,
                                                   enc_w2, enc_b2, (bf16*)encW);
  seq_kernel<<<32, 512, 0, stream>>>(encW, Wbu, Wtd, Wfx, b_iou, b_f, b_ih, b_hh,
                                     buh, encW);
  dec_kernel<<<(int)(NROWS / 8), 256, 0, stream>>>((const bf16*)buh, (const bf16*)encW,
                                                   cv, dec_w1, dec_b1, dec_w2, dec_b2,
                                                   (float*)d_out);
}